// Round 5
// baseline (4080.128 us; speedup 1.0000x reference)
//
#include <hip/hip_runtime.h>

#define BB 64
#define HH 1024
#define SS 512

typedef __attribute__((ext_vector_type(8))) short short8;
typedef __attribute__((ext_vector_type(4))) float f32x4;
typedef __attribute__((ext_vector_type(4))) unsigned u32x4;
typedef unsigned long long u64;

__device__ __forceinline__ unsigned short f2bf(float f) {
  union { float f; unsigned u; } v; v.f = f;
  unsigned r = v.u + 0x7fffu + ((v.u >> 16) & 1u);   // RNE
  return (unsigned short)(r >> 16);
}

// ---- prep: fp32 weights -> bf16; h buffer0 = tagged h0 (tag=0); buffer1 =
//      tag-0 poison (stale tags are then ALWAYS < t -> min-check suffices);
//      optionally x -> bf16 ----
__global__ void gru_prep(const float* __restrict__ wih, const float* __restrict__ whh,
                         const float* __restrict__ h0, const float* __restrict__ x,
                         unsigned short* __restrict__ wih_bf,
                         unsigned short* __restrict__ whh_bf,
                         unsigned* __restrict__ htag,
                         unsigned short* __restrict__ xbf, int do_x) {
  const int NT = gridDim.x * blockDim.x;
  const int tid = blockIdx.x * blockDim.x + threadIdx.x;
  for (int i = tid; i < 3 * HH * HH; i += NT) {
    wih_bf[i] = f2bf(wih[i]);
    whh_bf[i] = f2bf(whh[i]);
  }
  for (int i = tid; i < BB * HH; i += NT) {
    htag[i]           = (unsigned)f2bf(h0[i]);   // tag 0 in high16
    htag[BB * HH + i] = 0u;                      // buffer1: tag-0 poison (< any t>=1)
  }
  if (do_x)
    for (int i = tid; i < BB * SS * HH; i += NT) xbf[i] = f2bf(x[i]);
}

// ---- persistent GRU ----
// 256 WGs x 256 thr, 1 WG/CU. WG = (16 hidden cols c0) x (16-row batch quarter m0).
// K=1024 split across 4 waves; weights register-resident.
// h exchange: tagged u32 (tag=t in high16, bf16 h in low16), 2 buffers. Detect
// and fetch are the SAME sc0+sc1 load. ALL steady-loop loads are inline asm so
// the compiler inserts no hidden vmcnt(0); exact counted waits keep the h-bank
// and the out[]-store acks off every wait. h-bank for t+1 issued in epilogue t
// (head start ~1 RT). Validity: stale tags always < t (publish chain invariant
// + tag-0 poison) -> single min-tree + one compare. Retry BOUNDED.
__global__ __launch_bounds__(256, 1) void gru_main(
    const float* __restrict__ x, const unsigned short* __restrict__ xbf, const int use_xbf,
    const float* __restrict__ h0,
    const float* __restrict__ bih, const float* __restrict__ bhh,
    const unsigned short* __restrict__ wih_bf, const unsigned short* __restrict__ whh_bf,
    unsigned* __restrict__ htag, float* __restrict__ out) {
  __shared__ f32x4 ldsv[2 * 4 * 256];             // [buf][src_wave][elem] = 32 KB

  const int wg   = blockIdx.x;
  const int idx  = (wg >> 3) + (wg & 7) * 32;     // XCD swizzle (perf heuristic only)
  const int c0   = (idx >> 2) * 16;               // hidden colgroup base
  const int m0   = (idx & 3) * 16;                // batch quarter base
  const int wv   = threadIdx.x >> 6;
  const int ln   = threadIdx.x & 63;
  const int l15  = ln & 15;                       // A-frag batch row / epilogue col
  const int quad = ln >> 4;                       // A-frag k-subblock / epilogue rowoff
  const int kb   = wv * 256 + quad * 8;           // wave K window + A/B frag offset
  const int tid  = threadIdx.x;

  // ---- register-resident weights: B-frag rows n=c0+l15, k = kb + kk*32 + e ----
  const unsigned short* wib = wih_bf + (size_t)(c0 + l15) * HH + kb;
  const unsigned short* whb = whh_bf + (size_t)(c0 + l15) * HH + kb;
  short8 Wi[3][8], Wh[3][8];
#pragma unroll
  for (int g = 0; g < 3; ++g)
#pragma unroll
    for (int kk = 0; kk < 8; ++kk) {
      Wi[g][kk] = *(const short8*)(wib + (size_t)g * HH * HH + kk * 32);
      Wh[g][kk] = *(const short8*)(whb + (size_t)g * HH * HH + kk * 32);
    }

  const int j = c0 + l15;                         // hidden col this thread owns
  const float br   = bih[j] + bhh[j];
  const float bz   = bih[HH + j] + bhh[HH + j];
  const float bi_n = bih[2 * HH + j];
  const float bh_n = bhh[2 * HH + j];

  // fp32 master h: this thread owns (row brow, col j); epilogue mapping is the
  // identical (wv,quad,l15) decomposition of tid (verified index algebra).
  const int brow = m0 + wv * 4 + quad;
  float hreg = h0[brow * HH + j];

  const float*          xfp = x   + (size_t)(m0 + l15) * (SS * HH) + kb;
  const unsigned short* xbp = xbf + (size_t)(m0 + l15) * (SS * HH) + kb;
  const int hw_off = (m0 + l15) * HH + kb;        // u32 offset of lane's h window

// x fragments: asm loads (bf16 path) so the compiler emits NO vmem of its own
#define XL(i, off)                                                           \
  asm volatile("global_load_dwordx4 %0, %1, off offset:" #off " sc0"         \
               : "=v"(ax[i]) : "v"(xp))
#define ISSUE_AX(tt)                                                         \
  if (use_xbf) {                                                             \
    const unsigned short* xp = xbp + (size_t)(tt) * HH;                      \
    XL(0, 0);   XL(1, 64);  XL(2, 128); XL(3, 192);                          \
    XL(4, 256); XL(5, 320); XL(6, 384); XL(7, 448);                          \
  } else {                                                                   \
    const float* xp = xfp + (size_t)(tt) * HH;                               \
    _Pragma("unroll")                                                        \
    for (int kk = 0; kk < 8; ++kk) {                                         \
      float4 xa = *(const float4*)(xp + kk * 32);                            \
      float4 xb = *(const float4*)(xp + kk * 32 + 4);                        \
      short8 v;                                                              \
      v[0] = (short)f2bf(xa.x); v[1] = (short)f2bf(xa.y);                    \
      v[2] = (short)f2bf(xa.z); v[3] = (short)f2bf(xa.w);                    \
      v[4] = (short)f2bf(xb.x); v[5] = (short)f2bf(xb.y);                    \
      v[6] = (short)f2bf(xb.z); v[7] = (short)f2bf(xb.w);                    \
      ax[kk] = v;                                                            \
    }                                                                        \
  }

// 16 tagged-h 16B loads (bank = full 16-row x 256-col window), L1/L2-bypassing
#define HL(i, off)                                                           \
  asm volatile("global_load_dwordx4 %0, %1, off offset:" #off " sc0 sc1"     \
               : "=v"(hr[i]) : "v"(hb))
#define ISSUE_H(hb)                                                          \
  do {                                                                       \
    HL(0, 0);    HL(1, 16);   HL(2, 128);  HL(3, 144);                       \
    HL(4, 256);  HL(5, 272);  HL(6, 384);  HL(7, 400);                       \
    HL(8, 512);  HL(9, 528);  HL(10, 640); HL(11, 656);                      \
    HL(12, 768); HL(13, 784); HL(14, 896); HL(15, 912);                      \
  } while (0)

// validity: stale tags are always < t; fresh == t. min over 64 u32 words has
// high16 == t  <=>  min >= (t<<16). 63 v_min_u32 (tree) + 1 compare.
#define HCHECK(okv)                                                          \
  {                                                                          \
    unsigned q_[16];                                                         \
    _Pragma("unroll")                                                        \
    for (int i_ = 0; i_ < 16; ++i_) {                                        \
      unsigned a_ = hr[i_][0] < hr[i_][1] ? hr[i_][0] : hr[i_][1];           \
      unsigned b_ = hr[i_][2] < hr[i_][3] ? hr[i_][2] : hr[i_][3];           \
      q_[i_] = a_ < b_ ? a_ : b_;                                            \
    }                                                                        \
    _Pragma("unroll")                                                        \
    for (int s_ = 8; s_ > 0; s_ >>= 1)                                       \
      for (int i_ = 0; i_ < s_; ++i_)                                        \
        q_[i_] = q_[i_] < q_[i_ + s_] ? q_[i_] : q_[i_ + s_];                \
    okv = (q_[0] >= tagv);                                                   \
  }

#define HMFMA()                                                              \
  _Pragma("unroll")                                                          \
  for (int kk = 0; kk < 8; ++kk) {                                           \
    unsigned p0 = __builtin_amdgcn_perm(hr[2*kk][1],   hr[2*kk][0],   0x05040100u); \
    unsigned p1 = __builtin_amdgcn_perm(hr[2*kk][3],   hr[2*kk][2],   0x05040100u); \
    unsigned p2 = __builtin_amdgcn_perm(hr[2*kk+1][1], hr[2*kk+1][0], 0x05040100u); \
    unsigned p3 = __builtin_amdgcn_perm(hr[2*kk+1][3], hr[2*kk+1][2], 0x05040100u); \
    union { unsigned u[4]; short8 s; } uu = {{p0, p1, p2, p3}};              \
    a3 = __builtin_amdgcn_mfma_f32_16x16x32_bf16(uu.s, Wh[0][kk], a3, 0, 0, 0); \
    a4 = __builtin_amdgcn_mfma_f32_16x16x32_bf16(uu.s, Wh[1][kk], a4, 0, 0, 0); \
    a5 = __builtin_amdgcn_mfma_f32_16x16x32_bf16(uu.s, Wh[2][kk], a5, 0, 0, 0); \
  }

  short8 ax[8];
  u32x4 hr[16];

  // prologue: x(t=0) first, then h-bank(t=0) + 1 dummy so that vmcnt(17)
  // drains exactly the x loads and vmcnt(1) drains exactly the bank.
  ISSUE_AX(0);
  {
    const unsigned* hb = htag + hw_off;
    ISSUE_H(hb);
    u32x4 dj;
    asm volatile("global_load_dwordx4 %0, %1, off sc0 sc1" : "=v"(dj) : "v"(hb));
  }

#pragma unroll 1
  for (int t = 0; t < SS; ++t) {
    const unsigned tagv = (unsigned)t << 16;

    // ---- 1) retire x loads ONLY (A-bank stays in flight), then x-MFMAs ----
    // queue: [x8, (pub), A16, (out|dummy)] <= 26 -> vmcnt(17) drains x8(+pub)
    asm volatile("s_waitcnt vmcnt(17)" ::: "memory");
    __builtin_amdgcn_sched_barrier(0);
    f32x4 a0 = {0.f, 0.f, 0.f, 0.f}, a1 = a0, a2 = a0;
#pragma unroll
    for (int kk = 0; kk < 8; ++kk) {
      a0 = __builtin_amdgcn_mfma_f32_16x16x32_bf16(ax[kk], Wi[0][kk], a0, 0, 0, 0);
      a1 = __builtin_amdgcn_mfma_f32_16x16x32_bf16(ax[kk], Wi[1][kk], a1, 0, 0, 0);
      a2 = __builtin_amdgcn_mfma_f32_16x16x32_bf16(ax[kk], Wi[2][kk], a2, 0, 0, 0);
    }

    // ---- 2) first poll: vmcnt(1) retires the bank, leaves the out-store ----
    {
      int ok;
      asm volatile("s_waitcnt vmcnt(1)" ::: "memory");
      __builtin_amdgcn_sched_barrier(0);
      HCHECK(ok);
      if (!__all(ok)) {
        const unsigned* hb = htag + (t & 1) * (BB * HH) + hw_off;
#pragma unroll 1
        for (int round = 0; round < 4096; ++round) {   // bounded: no hang possible
          ISSUE_H(hb);
          asm volatile("s_waitcnt vmcnt(0)" ::: "memory");
          __builtin_amdgcn_sched_barrier(0);
          HCHECK(ok);
          if (__all(ok)) break;
          if (round > 7) __builtin_amdgcn_s_sleep(1);
        }
      }
    }

    // ---- 3) prefetch next x (flies under h-MFMA + epilogue) ----
    if (t + 1 < SS) { ISSUE_AX(t + 1); }

    // ---- 4) h-projection MFMAs (in-register v_perm unpack) ----
    f32x4 a3 = {0.f, 0.f, 0.f, 0.f}, a4 = a3, a5 = a3;
    HMFMA();
    a0 += a3;   // r gate: x-part + h-part combine
    a1 += a4;   // z gate: combine
                // n gate: a2 (x_n) and a5 (h_n) stay separate (r scales h_n)

    // ---- 5) transposed partials: 4 x ds_write_b128 per wave ----
    {
      f32x4* P = ldsv + (t & 1) * 1024 + wv * 256;
#pragma unroll
      for (int i = 0; i < 4; ++i) {
        f32x4 v = {a0[i], a1[i], a2[i], a5[i]};
        P[quad * 64 + i * 16 + l15] = v;
      }
    }
    __syncthreads();

    // ---- 6) epilogue on all 256 threads: 4 x ds_read_b128 reduce + gates;
    //         publish FIRST, then issue next h-bank, then out stores ----
    {
      const f32x4* P = ldsv + (t & 1) * 1024;
      f32x4 sv = P[tid] + P[256 + tid] + P[512 + tid] + P[768 + tid];
      float r = 1.f / (1.f + __expf(-(sv[0] + br)));
      float z = 1.f / (1.f + __expf(-(sv[1] + bz)));
      float pre = sv[2] + bi_n + r * (sv[3] + bh_n);
      float e2 = __expf(2.f * pre);
      float n = 1.f - 2.f / (e2 + 1.f);           // tanh
      float hnew = (1.f - z) * n + z * hreg;
      hreg = hnew;

      if (t + 1 < SS) {
        unsigned pk = (unsigned)f2bf(hnew) | ((unsigned)(t + 1) << 16);
        __hip_atomic_store(htag + ((t + 1) & 1) * (BB * HH) + brow * HH + j, pk,
                           __ATOMIC_RELAXED, __HIP_MEMORY_SCOPE_AGENT);
        const unsigned* hb = htag + ((t + 1) & 1) * (BB * HH) + hw_off;
        ISSUE_H(hb);                              // head start ~1 RT for t+1
      }
      asm volatile("" ::: "memory");              // pin out-store AFTER the issue
      __builtin_nontemporal_store(hnew,
          &out[(size_t)brow * (SS * HH) + (size_t)t * HH + j]);
      if (t == SS - 1)
        __builtin_nontemporal_store(hnew, &out[(size_t)BB * SS * HH + brow * HH + j]);
    }
    // next iteration uses the other LDS partial buffer — no tail sync needed
  }
#undef XL
#undef ISSUE_AX
#undef HL
#undef ISSUE_H
#undef HCHECK
#undef HMFMA
}

extern "C" void kernel_launch(void* const* d_in, const int* in_sizes, int n_in,
                              void* d_out, int out_size, void* d_ws, size_t ws_size,
                              hipStream_t stream) {
  const float* x   = (const float*)d_in[0];
  const float* h0  = (const float*)d_in[1];
  const float* wih = (const float*)d_in[2];
  const float* whh = (const float*)d_in[3];
  const float* bih = (const float*)d_in[4];
  const float* bhh = (const float*)d_in[5];
  float* out = (float*)d_out;

  char* ws = (char*)d_ws;
  const size_t off_whh = 6291456;            // 3*1024*1024*2
  const size_t off_h   = 12582912;           // tagged h: 2 x 64x1024 u32 = 512 KB
  const size_t off_x   = 13107200;           // after tagged-h buffers
  const size_t need_x  = off_x + (size_t)BB * SS * HH * 2;   // ~80 MB (GUARDED)

  unsigned short* wih_bf = (unsigned short*)ws;
  unsigned short* whh_bf = (unsigned short*)(ws + off_whh);
  unsigned*       htag   = (unsigned*)(ws + off_h);
  unsigned short* xbf    = (unsigned short*)(ws + off_x);
  const int use_xbf = (ws_size >= need_x) ? 1 : 0;

  hipLaunchKernelGGL(gru_prep, dim3(2048), dim3(256), 0, stream,
                     wih, whh, h0, x, wih_bf, whh_bf, htag, xbf, use_xbf);
  hipLaunchKernelGGL(gru_main, dim3(256), dim3(256), 0, stream,
                     x, xbf, use_xbf, h0, bih, bhh, wih_bf, whh_bf, htag, out);
}